// Round 6
// baseline (529.219 us; speedup 1.0000x reference)
//
#include <hip/hip_runtime.h>
#include <hip/hip_bf16.h>

#define D_IN 256
#define D_OUT 128
#define LN_EPS 1e-5f
#define NPB 256            // nodes per bucket (bucket = dst >> 8)
#define NCHUNK 512         // edge chunks (one block each) in count/part

typedef short bf16x8 __attribute__((ext_vector_type(8)));
typedef float f32x4 __attribute__((ext_vector_type(4)));
typedef unsigned short ushort_t;

__device__ __forceinline__ float b2f(ushort_t u) {
    union { unsigned int i; float f; } v; v.i = (unsigned int)u << 16; return v.f;
}
__device__ __forceinline__ ushort_t f2b(float f) {
    __hip_bfloat16 h = __float2bfloat16(f);
    return *reinterpret_cast<ushort_t*>(&h);
}

// ---------------- Kernel 0: pack+transpose f32 weights into bf16 Wt[n][k], n = [W | res_w] cols
__global__ void k_transpose(const float* __restrict__ w, const float* __restrict__ rw,
                            ushort_t* __restrict__ wt) {
    int idx = blockIdx.x * 256 + threadIdx.x;   // 65536 total
    int n = idx >> 8, k = idx & 255;
    float v = (n < 128) ? w[k * 128 + n] : rw[k * 128 + (n - 128)];
    wt[idx] = f2b(v);
}

// ---------------- Kernel 1: dual GEMM (bf16 MFMA internally, f32 in/out)
__launch_bounds__(256)
__global__ void k_gemm(const float* __restrict__ x, const ushort_t* __restrict__ wt,
                       const float* __restrict__ bias, const float* __restrict__ res_b,
                       ushort_t* __restrict__ support, float* __restrict__ out, int n_nodes) {
    __shared__ ushort_t As[64 * 40];
    __shared__ ushort_t Bs[256 * 40];

    const int tid = threadIdx.x;
    const int m0 = blockIdx.x * 64;
    const int wv = tid >> 6, lane = tid & 63;
    const int lm = lane & 15, quad = lane >> 4;
    const int mh = wv >> 1;
    const int nh = wv & 1;

    f32x4 acc[2][8];
#pragma unroll
    for (int i = 0; i < 2; i++)
#pragma unroll
        for (int j = 0; j < 8; j++) acc[i][j] = 0.0f;

    const int arow = tid >> 2, aseg = tid & 3;
    const bool arow_ok = (m0 + arow) < n_nodes;
    const float* xrow = x + (long)(m0 + arow) * D_IN + aseg * 8;

    for (int kc = 0; kc < 8; kc++) {
        __syncthreads();
        {
            bf16x8 av = {0, 0, 0, 0, 0, 0, 0, 0};
            if (arow_ok) {
                f32x4 p0 = *(const f32x4*)(xrow + kc * 32);
                f32x4 p1 = *(const f32x4*)(xrow + kc * 32 + 4);
#pragma unroll
                for (int j = 0; j < 4; j++) { av[j] = (short)f2b(p0[j]); av[4 + j] = (short)f2b(p1[j]); }
            }
            *(bf16x8*)(&As[arow * 40 + aseg * 8]) = av;
        }
#pragma unroll
        for (int i = 0; i < 4; i++) {
            int n = (tid >> 2) + i * 64;
            bf16x8 v = *(const bf16x8*)(wt + n * 256 + kc * 32 + aseg * 8);
            *(bf16x8*)(&Bs[n * 40 + aseg * 8]) = v;
        }
        __syncthreads();

        bf16x8 afr0 = *(const bf16x8*)(&As[(mh * 32 + lm) * 40 + quad * 8]);
        bf16x8 afr1 = *(const bf16x8*)(&As[(mh * 32 + 16 + lm) * 40 + quad * 8]);
#pragma unroll
        for (int nt = 0; nt < 8; nt++) {
            bf16x8 bfr = *(const bf16x8*)(&Bs[(nh * 128 + nt * 16 + lm) * 40 + quad * 8]);
            acc[0][nt] = __builtin_amdgcn_mfma_f32_16x16x32_bf16(afr0, bfr, acc[0][nt], 0, 0, 0);
            acc[1][nt] = __builtin_amdgcn_mfma_f32_16x16x32_bf16(afr1, bfr, acc[1][nt], 0, 0, 0);
        }
    }

#pragma unroll
    for (int i = 0; i < 2; i++) {
#pragma unroll
        for (int nt = 0; nt < 8; nt++) {
            int col = nh * 128 + nt * 16 + lm;
#pragma unroll
            for (int r = 0; r < 4; r++) {
                int node = m0 + mh * 32 + i * 16 + quad * 4 + r;
                if (node >= n_nodes) continue;
                float v = acc[i][nt][r];
                if (col < 128) {
                    support[(long)node * 128 + col] = f2b(v);
                } else {
                    int c2 = col - 128;
                    float t = v + res_b[c2];
                    t = t > 0.0f ? t : 0.0f;
                    out[(long)node * 128 + c2] = t + bias[c2];
                }
            }
        }
    }
}

// ---------------- Kernel 2: per-chunk bucket histogram -> cntmat[bucket][chunk] (ushort)
__launch_bounds__(256)
__global__ void k_count(const int* __restrict__ ei, ushort_t* __restrict__ cntmat,
                        int E, int chunk, int nbuck) {
    __shared__ int h[512];
    int c = blockIdx.x, t = threadIdx.x;
    h[t] = 0; h[t + 256] = 0;
    __syncthreads();
    int lo = c * chunk, hi = min(lo + chunk, E);
    for (int e = lo + t; e < hi; e += 256)
        atomicAdd(&h[(unsigned)ei[E + e] >> 8], 1);
    __syncthreads();
    for (int i = t; i < nbuck; i += 256)
        cntmat[i * NCHUNK + c] = (ushort_t)h[i];
}

// ---------------- Kernel 3a: scan each bucket row of cntmat (exclusive), rowsum out
__launch_bounds__(256)
__global__ void k_scan1(ushort_t* __restrict__ cntmat, int* __restrict__ rowsum) {
    __shared__ int sh[256];
    int b = blockIdx.x, t = threadIdx.x;
    int v0 = cntmat[b * NCHUNK + 2 * t];
    int v1 = cntmat[b * NCHUNK + 2 * t + 1];
    int s = v0 + v1;
    sh[t] = s;
    __syncthreads();
    for (int off = 1; off < 256; off <<= 1) {
        int x = sh[t]; int add = (t >= off) ? sh[t - off] : 0;
        __syncthreads(); sh[t] = x + add; __syncthreads();
    }
    int e = sh[t] - s;
    cntmat[b * NCHUNK + 2 * t] = (ushort_t)e;
    cntmat[b * NCHUNK + 2 * t + 1] = (ushort_t)(e + v0);
    if (t == 255) rowsum[b] = sh[255];
}

// ---------------- Kernel 3b: scan bucket sums -> bucket_base; also offs[N]=E
__launch_bounds__(512)
__global__ void k_scan2(const int* __restrict__ rowsum, int* __restrict__ bucket_base,
                        int* __restrict__ offs, int n_nodes, int E, int nbuck) {
    __shared__ int sh[512];
    int t = threadIdx.x;
    int v = (t < nbuck) ? rowsum[t] : 0;
    sh[t] = v;
    __syncthreads();
    for (int off = 1; off < 512; off <<= 1) {
        int x = sh[t]; int add = (t >= off) ? sh[t - off] : 0;
        __syncthreads(); sh[t] = x + add; __syncthreads();
    }
    if (t < nbuck) bucket_base[t] = sh[t] - v;
    if (t == nbuck - 1) bucket_base[nbuck] = sh[t];
    if (t == 0) offs[n_nodes] = E;
}

// ---------------- Kernel 4: partition edges into buckets (block-private sub-regions)
// pk = dl<<17 | src  (4B), pw = weight bf16 (2B)
__launch_bounds__(256)
__global__ void k_part(const int* __restrict__ ei, const float* __restrict__ ew,
                       const ushort_t* __restrict__ cntmat, const int* __restrict__ bucket_base,
                       int* __restrict__ pk, ushort_t* __restrict__ pw, int E, int chunk, int nbuck) {
    __shared__ int cur[512];
    int c = blockIdx.x, t = threadIdx.x;
    for (int i = t; i < nbuck; i += 256)
        cur[i] = bucket_base[i] + (int)cntmat[i * NCHUNK + c];
    __syncthreads();
    int lo = c * chunk, hi = min(lo + chunk, E);
    for (int e = lo + t; e < hi; e += 256) {
        int src = ei[e];
        int dst = ei[E + e];
        float w = ew[e];
        int b = (unsigned)dst >> 8;
        int pos = atomicAdd(&cur[b], 1);
        pk[pos] = src | ((dst & 255) << 17);
        pw[pos] = f2b(w);
    }
}

// ---------------- Kernel 5: per-bucket node-sort: write sorted (src, w) + offs
__launch_bounds__(512)
__global__ void k_build(const int* __restrict__ pk, const ushort_t* __restrict__ pw,
                        const int* __restrict__ bucket_base, int* __restrict__ sk,
                        ushort_t* __restrict__ sw, int* __restrict__ offs, int n_nodes) {
    __shared__ int h[256];
    __shared__ int psum[256];
    int b = blockIdx.x, t = threadIdx.x;
    int start = bucket_base[b], end = bucket_base[b + 1];
    if (t < 256) h[t] = 0;
    __syncthreads();
    for (int i = start + t; i < end; i += 512)
        atomicAdd(&h[(unsigned)pk[i] >> 17], 1);
    __syncthreads();
    int cnt = 0;
    if (t < 256) { cnt = h[t]; psum[t] = cnt; }
    __syncthreads();
    for (int off = 1; off < 256; off <<= 1) {
        int x = 0, add = 0;
        if (t < 256) { x = psum[t]; add = (t >= off) ? psum[t - off] : 0; }
        __syncthreads();
        if (t < 256) psum[t] = x + add;
        __syncthreads();
    }
    if (t < 256) {
        int excl = psum[t] - cnt;
        int node = b * NPB + t;
        if (node < n_nodes) offs[node] = start + excl;
        h[t] = start + excl;    // absolute cursor
    }
    __syncthreads();
    for (int i = start + t; i < end; i += 512) {
        int key = pk[i];
        int dl = (unsigned)key >> 17;
        int pos = atomicAdd(&h[dl], 1);
        sk[pos] = key & 131071;   // plain src
        sw[pos] = pw[i];
    }
}

// ---------------- Kernel 6: gather-aggregate + residual + LayerNorm (wave per node,
// half-wave per edge: 32 lanes x 8B cover one support row; 2 edges per gather step)
__launch_bounds__(256)
__global__ void k_agg_ln(const ushort_t* __restrict__ support, const int* __restrict__ offs,
                         const int* __restrict__ sk, const ushort_t* __restrict__ sw,
                         const float* __restrict__ gamma, const float* __restrict__ beta,
                         float* __restrict__ out, int n_nodes) {
    int gw = (int)((blockIdx.x * blockDim.x + threadIdx.x) >> 6);
    int lane = threadIdx.x & 63;
    int nw = (int)((gridDim.x * blockDim.x) >> 6);
    const int fl = lane & 31;         // feature group: features fl*4 .. fl*4+3
    const bool hi_half = lane >= 32;  // half 1 processes odd edges

    f32x4 g = *(const f32x4*)(gamma + fl * 4);
    f32x4 bb = *(const f32x4*)(beta + fl * 4);

    for (int node = gw; node < n_nodes; node += nw) {
        int start = offs[node], end = offs[node + 1];
        float a0 = 0.0f, a1 = 0.0f, a2 = 0.0f, a3 = 0.0f;
        for (int base = start; base < end; base += 64) {
            int n = end - base; if (n > 64) n = 64;
            int key = 0, wbits = 0;
            if (lane < n) {
                key = sk[base + lane];
                wbits = (int)sw[base + lane];   // lanes >= n stay 0 -> w=0
            }
            int npair = (n + 1) >> 1;
            for (int j = 0; j < npair; j++) {
                int s0 = __builtin_amdgcn_readlane(key, 2 * j);
                int s1 = __builtin_amdgcn_readlane(key, 2 * j + 1);
                float w0 = b2f((ushort_t)__builtin_amdgcn_readlane(wbits, 2 * j));
                float w1 = b2f((ushort_t)__builtin_amdgcn_readlane(wbits, 2 * j + 1));
                int ssel = hi_half ? s1 : s0;
                float wsel = hi_half ? w1 : w0;
                uint2 v = *(const uint2*)(support + (long)ssel * 128 + fl * 4);
                float f0 = __uint_as_float(v.x << 16);
                float f1 = __uint_as_float(v.x & 0xffff0000u);
                float f2 = __uint_as_float(v.y << 16);
                float f3 = __uint_as_float(v.y & 0xffff0000u);
                a0 += wsel * f0; a1 += wsel * f1; a2 += wsel * f2; a3 += wsel * f3;
            }
        }
        // merge the two half-wave partial sums (lane l and l+32 hold same features)
        a0 += __shfl_xor(a0, 32, 64);
        a1 += __shfl_xor(a1, 32, 64);
        a2 += __shfl_xor(a2, 32, 64);
        a3 += __shfl_xor(a3, 32, 64);

        // residual (bias + relu(x@res_w+res_b)) already in out
        f32x4 r = *(const f32x4*)(out + (long)node * 128 + fl * 4);
        float t0 = a0 + r[0], t1 = a1 + r[1], t2 = a2 + r[2], t3 = a3 + r[3];
        float s = t0 + t1 + t2 + t3;
        float ss = t0 * t0 + t1 * t1 + t2 * t2 + t3 * t3;
#pragma unroll
        for (int off = 1; off < 32; off <<= 1) {
            s += __shfl_xor(s, off, 64);
            ss += __shfl_xor(ss, off, 64);
        }
        float mean = s * (1.0f / 128.0f);
        float var = ss * (1.0f / 128.0f) - mean * mean;
        float rstd = rsqrtf(var + LN_EPS);
        if (!hi_half) {
            f32x4 o;
            o[0] = (t0 - mean) * rstd * g[0] + bb[0];
            o[1] = (t1 - mean) * rstd * g[1] + bb[1];
            o[2] = (t2 - mean) * rstd * g[2] + bb[2];
            o[3] = (t3 - mean) * rstd * g[3] + bb[3];
            *(f32x4*)(out + (long)node * 128 + fl * 4) = o;
        }
    }
}

extern "C" void kernel_launch(void* const* d_in, const int* in_sizes, int n_in,
                              void* d_out, int out_size, void* d_ws, size_t ws_size,
                              hipStream_t stream) {
    const float* x      = (const float*)d_in[0];
    const float* weight = (const float*)d_in[1];
    const float* bias   = (const float*)d_in[2];
    const float* res_w  = (const float*)d_in[3];
    const float* res_b  = (const float*)d_in[4];
    const float* gamma  = (const float*)d_in[5];
    const float* beta   = (const float*)d_in[6];
    const float* ew     = (const float*)d_in[7];
    const int*   ei     = (const int*)d_in[8];

    const int E = in_sizes[7];
    const int n_nodes = in_sizes[0] / D_IN;
    const int nbuck = (n_nodes + NPB - 1) / NPB;     // <= 512
    const int chunk = (E + NCHUNK - 1) / NCHUNK;
    float* out = (float*)d_out;

    // workspace layout (256B-aligned), ~64.8 MB (== R5 proven usage)
    // region0 overlays wt (live: transpose..gemm) with cntmat/rowsum/bucket_base (live: count..build)
    char* ws = (char*)d_ws;
    size_t off = 0;
    auto alloc = [&](size_t bytes) { void* p = ws + off; off = (off + bytes + 255) & ~(size_t)255; return p; };
    size_t r0 = (size_t)nbuck * NCHUNK * 2 + 8192;               // cntmat + rowsum + bb
    if (r0 < 256 * 256 * 2) r0 = 256 * 256 * 2;                  // at least wt size
    char* region0 = (char*)alloc(r0);
    ushort_t* wt       = (ushort_t*)region0;
    ushort_t* cntmat   = (ushort_t*)region0;
    int* rowsum        = (int*)(region0 + (size_t)nbuck * NCHUNK * 2);
    int* bucket_base   = rowsum + 512;
    ushort_t* support  = (ushort_t*)alloc((size_t)n_nodes * 128 * 2);   // 25.6 MB
    int* offs          = (int*)alloc((size_t)(n_nodes + 1) * 4);        // 400 KB
    int* pk            = (int*)alloc((size_t)E * 4);                    // 12.8 MB
    ushort_t* pw       = (ushort_t*)alloc((size_t)E * 2);               // 6.4 MB
    int* sk            = (int*)alloc((size_t)E * 4);                    // 12.8 MB
    ushort_t* sw       = (ushort_t*)alloc((size_t)E * 2);               // 6.4 MB

    k_transpose<<<256, 256, 0, stream>>>(weight, res_w, wt);
    k_gemm<<<(n_nodes + 63) / 64, 256, 0, stream>>>(x, wt, bias, res_b, support, out, n_nodes);
    k_count<<<NCHUNK, 256, 0, stream>>>(ei, cntmat, E, chunk, nbuck);
    k_scan1<<<nbuck, 256, 0, stream>>>(cntmat, rowsum);
    k_scan2<<<1, 512, 0, stream>>>(rowsum, bucket_base, offs, n_nodes, E, nbuck);
    k_part<<<NCHUNK, 256, 0, stream>>>(ei, ew, cntmat, bucket_base, pk, pw, E, chunk, nbuck);
    k_build<<<nbuck, 512, 0, stream>>>(pk, pw, bucket_base, sk, sw, offs, n_nodes);
    k_agg_ln<<<4096, 256, 0, stream>>>(support, offs, sk, sw, gamma, beta, out, n_nodes);
}